// Round 1
// baseline (618.279 us; speedup 1.0000x reference)
//
#include <hip/hip_runtime.h>
#include <math.h>

#define BSZ 256
#define S 196
#define RDIM 2048
#define ADIM 512

// ---------------- K1: split-K tiled f32 GEMM: partial[z][b][a] = h@W_h chunk ----
#define BM 64
#define BN 64
#define BK 32
#define SPLITK 8
#define KCHUNK (RDIM / SPLITK) // 256

__global__ __launch_bounds__(256) void gemm_splitk(
    const float* __restrict__ h, const float* __restrict__ Wh,
    float* __restrict__ partial)
{
    __shared__ float As[BK][BM + 4];  // +4 pad: breaks 8-way bank conflict on transpose store
    __shared__ float Bs[BK][BN];
    const int tid = threadIdx.x;
    const int n0 = blockIdx.x * BN;
    const int m0 = blockIdx.y * BM;
    const int kz = blockIdx.z;
    const int kbeg = kz * KCHUNK;

    const int tx = tid & 15, ty = tid >> 4;
    float acc[4][4] = {};

    for (int kt = 0; kt < KCHUNK; kt += BK) {
        // A tile: h[m0..+63][kbeg+kt..+31] -> As[k][m] (transposed)
        {
            int idx = tid;
            #pragma unroll
            for (int rep = 0; rep < 2; ++rep, idx += 256) {
                int row = idx >> 3;            // 0..63
                int c4  = (idx & 7) << 2;      // 0..28
                const float4 v = *(const float4*)(h + (size_t)(m0 + row) * RDIM + kbeg + kt + c4);
                As[c4 + 0][row] = v.x;
                As[c4 + 1][row] = v.y;
                As[c4 + 2][row] = v.z;
                As[c4 + 3][row] = v.w;
            }
        }
        // B tile: Wh[kbeg+kt..+31][n0..+63] -> Bs[k][n]
        {
            int idx = tid;
            #pragma unroll
            for (int rep = 0; rep < 2; ++rep, idx += 256) {
                int row = idx >> 4;            // 0..31
                int c4  = (idx & 15) << 2;     // 0..60
                *(float4*)(&Bs[row][c4]) = *(const float4*)(Wh + (size_t)(kbeg + kt + row) * ADIM + n0 + c4);
            }
        }
        __syncthreads();
        #pragma unroll
        for (int k = 0; k < BK; ++k) {
            float4 a4 = *(const float4*)(&As[k][ty << 2]);
            float4 b4 = *(const float4*)(&Bs[k][tx << 2]);
            float av[4] = {a4.x, a4.y, a4.z, a4.w};
            float bv[4] = {b4.x, b4.y, b4.z, b4.w};
            #pragma unroll
            for (int i = 0; i < 4; ++i)
                #pragma unroll
                for (int j = 0; j < 4; ++j)
                    acc[i][j] = fmaf(av[i], bv[j], acc[i][j]);
        }
        __syncthreads();
    }
    float* outp = partial + (size_t)kz * BSZ * ADIM;
    #pragma unroll
    for (int i = 0; i < 4; ++i) {
        float4 v = {acc[i][0], acc[i][1], acc[i][2], acc[i][3]};
        *(float4*)(outp + (size_t)(m0 + (ty << 2) + i) * ADIM + n0 + (tx << 2)) = v;
    }
}

// ---------------- K1b: reduce split-K partials + bias -> att_h[b][a] ----------
__global__ __launch_bounds__(256) void reduce_addbias(
    const float* __restrict__ partial, const float* __restrict__ b_h,
    float* __restrict__ att_h)
{
    int i = blockIdx.x * 256 + threadIdx.x;   // 0 .. B*A-1
    float s = b_h[i & (ADIM - 1)];
    #pragma unroll
    for (int z = 0; z < SPLITK; ++z) s += partial[(size_t)z * BSZ * ADIM + i];
    att_h[i] = s;
}

// ---------------- K2: scores[b,s] = sum_a tanh(p + att_h) * W_a + b_a ---------
__device__ __forceinline__ float tanh_fast(float x) {
    x = fminf(15.f, fmaxf(-15.f, x));
    float e = __expf(2.f * x);
    return (e - 1.f) / (e + 1.f);
}

__global__ __launch_bounds__(256) void scores_kernel(
    const float* __restrict__ p_att, const float* __restrict__ att_h,
    const unsigned char* __restrict__ mask,
    const float* __restrict__ W_a, const float* __restrict__ b_a,
    float* __restrict__ scores)
{
    const int gtid = blockIdx.x * 256 + threadIdx.x;
    const int wave = gtid >> 6;              // one wave64 per (b,s)
    const int lane = threadIdx.x & 63;
    const int b = wave / S, s = wave % S;

    const float* prow = p_att + ((size_t)b * S + s) * ADIM;
    const float* arow = att_h + (size_t)b * ADIM;

    float acc = 0.f;
    #pragma unroll
    for (int c = 0; c < 2; ++c) {
        const int a = c * 256 + lane * 4;
        float4 p4 = *(const float4*)(prow + a);
        float4 h4 = *(const float4*)(arow + a);
        float4 w4 = *(const float4*)(W_a + a);
        acc = fmaf(tanh_fast(p4.x + h4.x), w4.x, acc);
        acc = fmaf(tanh_fast(p4.y + h4.y), w4.y, acc);
        acc = fmaf(tanh_fast(p4.z + h4.z), w4.z, acc);
        acc = fmaf(tanh_fast(p4.w + h4.w), w4.w, acc);
    }
    #pragma unroll
    for (int off = 32; off; off >>= 1) acc += __shfl_xor(acc, off, 64);
    if (lane == 0) {
        float sc = acc + b_a[0];
        if (mask[wave]) sc = -100000000.0f;
        scores[wave] = sc;
    }
}

// ---------------- K3: softmax over s per b (one wave per b) -------------------
__global__ void softmax_kernel(const float* __restrict__ scores,
                               float* __restrict__ weight)
{
    const int b = blockIdx.x;
    const int lane = threadIdx.x;            // 0..63
    const float* srow = scores + (size_t)b * S;
    float v[4];
    float m = -INFINITY;
    #pragma unroll
    for (int i = 0; i < 4; ++i) {
        int s = i * 64 + lane;
        v[i] = (s < S) ? srow[s] : -INFINITY;
        m = fmaxf(m, v[i]);
    }
    #pragma unroll
    for (int off = 32; off; off >>= 1) m = fmaxf(m, __shfl_xor(m, off, 64));
    float sum = 0.f;
    #pragma unroll
    for (int i = 0; i < 4; ++i) {
        int s = i * 64 + lane;
        v[i] = (s < S) ? __expf(v[i] - m) : 0.f;
        sum += v[i];
    }
    #pragma unroll
    for (int off = 32; off; off >>= 1) sum += __shfl_xor(sum, off, 64);
    const float inv = 1.f / sum;
    float* wrow = weight + (size_t)b * S;
    #pragma unroll
    for (int i = 0; i < 4; ++i) {
        int s = i * 64 + lane;
        if (s < S) wrow[s] = v[i] * inv;
    }
}

// ---------------- K4: att_res[b,r] = sum_s weight[b,s] * att_feats[b,s,r] ----
#define RCHUNK 1024  // 256 threads * float4
__global__ __launch_bounds__(256) void wsum_kernel(
    const float* __restrict__ feats, const float* __restrict__ weight,
    float* __restrict__ out)
{
    __shared__ float wsm[S];
    const int b  = blockIdx.x >> 1;     // 2 r-chunks per b
    const int rc = blockIdx.x & 1;
    const int tid = threadIdx.x;
    if (tid < S) wsm[tid] = weight[(size_t)b * S + tid];
    __syncthreads();

    const int r0 = rc * RCHUNK + tid * 4;
    const float* base = feats + (size_t)b * S * RDIM + r0;
    float4 acc = {0.f, 0.f, 0.f, 0.f};
    #pragma unroll 4
    for (int s = 0; s < S; ++s) {       // 196 = 4*49, clean unroll
        const float w = wsm[s];
        const float4 f = *(const float4*)(base + (size_t)s * RDIM);
        acc.x = fmaf(w, f.x, acc.x);
        acc.y = fmaf(w, f.y, acc.y);
        acc.z = fmaf(w, f.z, acc.z);
        acc.w = fmaf(w, f.w, acc.w);
    }
    *(float4*)(out + (size_t)b * RDIM + r0) = acc;
}

extern "C" void kernel_launch(void* const* d_in, const int* in_sizes, int n_in,
                              void* d_out, int out_size, void* d_ws, size_t ws_size,
                              hipStream_t stream) {
    const float* h         = (const float*)d_in[0];
    const float* att_feats = (const float*)d_in[1];
    const float* p_att     = (const float*)d_in[2];
    const unsigned char* mask = (const unsigned char*)d_in[3]; // all-false; any byte repr works
    const float* W_h       = (const float*)d_in[4];
    const float* b_h       = (const float*)d_in[5];
    const float* W_a       = (const float*)d_in[6];
    const float* b_a       = (const float*)d_in[7];
    float* out = (float*)d_out;

    char* ws = (char*)d_ws;
    float* partial = (float*)ws;                                  // 8*256*512 f32 = 4 MB
    float* att_h   = (float*)(ws + (size_t)SPLITK * BSZ * ADIM * 4); // 512 KB
    float* scores  = att_h + BSZ * ADIM;                          // 256*196 f32
    float* weight  = scores + BSZ * S;                            // 256*196 f32

    gemm_splitk<<<dim3(ADIM / BN, BSZ / BM, SPLITK), 256, 0, stream>>>(h, W_h, partial);
    reduce_addbias<<<(BSZ * ADIM) / 256, 256, 0, stream>>>(partial, b_h, att_h);
    scores_kernel<<<(BSZ * S * 64) / 256, 256, 0, stream>>>(p_att, att_h, mask, W_a, b_a, scores);
    softmax_kernel<<<BSZ, 64, 0, stream>>>(scores, weight);
    wsum_kernel<<<BSZ * 2, 256, 0, stream>>>(att_feats, weight, out);
}